// Round 21
// baseline (686.060 us; speedup 1.0000x reference)
//
#include <hip/hip_runtime.h>

typedef float f32x4 __attribute__((ext_vector_type(4)));

#define TSTEPS 500
#define BDIM 64
#define CIN 512
#define COUT 512
#define MTOT (TSTEPS * BDIM)   // 32000
#define NCH (BDIM * CIN)       // 32768
#define SNEUR (BDIM * COUT)    // 32768
#define OUTN ((size_t)TSTEPS * SNEUR + SNEUR)

#define AL64 0.95122942450071400909   // math.exp(-0.001/0.02), f64
#define BL64 (1.0 - AL64)

#define BUF_BYTES 65536000ull  // one [32000,512] f32 plane
#define WS_NEED (3ull * BUF_BYTES)

__global__ __launch_bounds__(256) void fill_const_f32(
    float* __restrict__ p, size_t n, float c) {
  size_t i = (size_t)blockIdx.x * 256 + threadIdx.x;
  const size_t stride = (size_t)gridDim.x * 256;
  for (; i < n; i += stride) p[i] = c;
}

// ---------------------------------------------------------------------------
// f32 trace scan (np-exact): tr = fl(fl(a*tr) + x)   [proven R13]
// 64-thread blocks x 512: covers all 256 CUs (128x256 left half idle).
// ---------------------------------------------------------------------------
__global__ __launch_bounds__(64) void trace32(
    const float* __restrict__ X, float* __restrict__ TR,
    const float* __restrict__ alpha) {
  const int j = blockIdx.x * 64 + threadIdx.x;  // b*512 + ci
  const float a = fminf(fmaxf(alpha[0], 0.0f), 0.9999f);
  float tr = 0.0f;
#pragma unroll 20
  for (int t = 0; t < TSTEPS; ++t) {
    float x = X[(size_t)t * NCH + j];
    tr = __fadd_rn(__fmul_rn(a, tr), x);
    TR[(size_t)t * NCH + j] = tr;
  }
}

// ---------------------------------------------------------------------------
// Head/tail split GEMM, BK=32, TRUE double-buffered LDS (one barrier/tile).
// Geometry: BM=64 x BN=128, 256 thr, 4x8/thread, 2 chain-sets (64 accs) —
// the proven LDS-ratio optimum (8rc/(2r+c)=16) under the 128-VGPR cliff.
// Reduction order bit-identical to R13..R20: k = kt*32 + kg*4 + k2 strictly
// ascending per chain; split at k=384 (BLAS KC); combine
// fadd(fadd(xH,xT), fadd(tH,tT)). XCD-chunked swizzle (2000 = 8 x 250).
// PHASE 0: head (tiles 0..12) -> PHx/PHt partials.
// PHASE 1: tail (tiles 12..16), combine, CUR in-place over PHx.
// ---------------------------------------------------------------------------
template <int PHASE>
__global__ __launch_bounds__(256) void gemmDB(
    const float* __restrict__ X, const float* __restrict__ TR,
    const float* __restrict__ W, float* __restrict__ PHx,
    float* __restrict__ PHt) {
  __shared__ __align__(16) float Asx[2][64][36];  // 2 bufs, padded
  __shared__ __align__(16) float Ast[2][64][36];
  __shared__ __align__(16) float Bs[2][32][132];
  const int tid = threadIdx.x;
  const int ty = tid >> 4, tx = tid & 15;

  const int fid = blockIdx.x;
  const int swz = (fid & 7) * 250 + (fid >> 3);
  const int bm = (swz >> 2) * 64;   // 500 row-panels
  const int bn = (swz & 3) * 128;   // 4 col-panels (fastest -> same XCD)

  const int ar = tid >> 2, akb = (tid & 3) * 8;  // A loader: 64 rows x 32 k
  const int bk = tid >> 3, bc4 = (tid & 7) * 4;  // B loader: 32 k x 128 n

  const int KT0 = PHASE ? 12 : 0;
  const int KT1 = PHASE ? 16 : 12;

  const float* gx = X + (size_t)(bm + ar) * CIN + KT0 * 32 + akb;
  const float* gt = TR + (size_t)(bm + ar) * CIN + KT0 * 32 + akb;
  const float* gw = W + (size_t)(KT0 * 32 + bk) * COUT + bn + bc4;

  float xA[4][8] = {{0.0f}}, tA[4][8] = {{0.0f}};

  // prologue: stage tile KT0 into buf 0
  {
    *(f32x4*)&Asx[0][ar][akb]     = *(const f32x4*)gx;
    *(f32x4*)&Asx[0][ar][akb + 4] = *(const f32x4*)(gx + 4);
    *(f32x4*)&Ast[0][ar][akb]     = *(const f32x4*)gt;
    *(f32x4*)&Ast[0][ar][akb + 4] = *(const f32x4*)(gt + 4);
#pragma unroll
    for (int q = 0; q < 4; ++q)
      *(f32x4*)&Bs[0][bk][bc4 + q * 32] = *(const f32x4*)(gw + q * 32);
  }
  __syncthreads();

  for (int kt = KT0; kt < KT1; ++kt) {
    const int cur = (kt - KT0) & 1;
    if (kt + 1 < KT1) {  // stage next tile into the other buffer (no barrier)
      gx += 32; gt += 32; gw += 32 * COUT;
      f32x4 nx0 = *(const f32x4*)gx, nx1 = *(const f32x4*)(gx + 4);
      f32x4 nt0 = *(const f32x4*)gt, nt1 = *(const f32x4*)(gt + 4);
      *(f32x4*)&Asx[cur ^ 1][ar][akb]     = nx0;
      *(f32x4*)&Asx[cur ^ 1][ar][akb + 4] = nx1;
      *(f32x4*)&Ast[cur ^ 1][ar][akb]     = nt0;
      *(f32x4*)&Ast[cur ^ 1][ar][akb + 4] = nt1;
#pragma unroll
      for (int q = 0; q < 4; ++q) {
        f32x4 nw = *(const f32x4*)(gw + q * 32);
        *(f32x4*)&Bs[cur ^ 1][bk][bc4 + q * 32] = nw;
      }
    }
#pragma unroll
    for (int kg = 0; kg < 8; ++kg) {
      f32x4 ax[4], at4[4];
#pragma unroll
      for (int i = 0; i < 4; ++i) {
        ax[i] = *(const f32x4*)&Asx[cur][ty * 4 + i][kg * 4];
        at4[i] = *(const f32x4*)&Ast[cur][ty * 4 + i][kg * 4];
      }
#pragma unroll
      for (int k2 = 0; k2 < 4; ++k2) {
        f32x4 bL = *(const f32x4*)&Bs[cur][kg * 4 + k2][tx * 4];
        f32x4 bH = *(const f32x4*)&Bs[cur][kg * 4 + k2][64 + tx * 4];
#pragma unroll
        for (int i = 0; i < 4; ++i)
#pragma unroll
          for (int j = 0; j < 4; ++j) {
            xA[i][j]     = fmaf(ax[i][k2], bL[j], xA[i][j]);
            xA[i][4 + j] = fmaf(ax[i][k2], bH[j], xA[i][4 + j]);
            tA[i][j]     = fmaf(at4[i][k2], bL[j], tA[i][j]);
            tA[i][4 + j] = fmaf(at4[i][k2], bH[j], tA[i][4 + j]);
          }
      }
    }
    __syncthreads();  // next-buf writes visible; cur reads done (one/tile)
  }

#pragma unroll
  for (int i = 0; i < 4; ++i) {
    const size_t row = (size_t)(bm + ty * 4 + i);
    const size_t iL = row * COUT + bn + tx * 4;
    const size_t iH = row * COUT + bn + 64 + tx * 4;
    f32x4 xL, xH2, tL, tH2;
#pragma unroll
    for (int j = 0; j < 4; ++j) {
      xL[j] = xA[i][j];  xH2[j] = xA[i][4 + j];
      tL[j] = tA[i][j];  tH2[j] = tA[i][4 + j];
    }
    if (PHASE == 0) {
      *(f32x4*)&PHx[iL] = xL;   *(f32x4*)&PHx[iH] = xH2;
      *(f32x4*)&PHt[iL] = tL;   *(f32x4*)&PHt[iH] = tH2;
    } else {
      f32x4 hxL = *(const f32x4*)&PHx[iL];
      f32x4 hxH = *(const f32x4*)&PHx[iH];
      f32x4 htL = *(const f32x4*)&PHt[iL];
      f32x4 htH = *(const f32x4*)&PHt[iH];
      f32x4 oL, oH;
#pragma unroll
      for (int j = 0; j < 4; ++j) {
        // cur = fadd(fadd(xH,xT), fadd(tH,tT))  — proven combine order
        oL[j] = __fadd_rn(__fadd_rn(hxL[j], xL[j]), __fadd_rn(htL[j], tL[j]));
        oH[j] = __fadd_rn(__fadd_rn(hxH[j], xH2[j]), __fadd_rn(htH[j], tH2[j]));
      }
      *(f32x4*)&PHx[iL] = oL;  // in-place: PHx becomes CUR
      *(f32x4*)&PHx[iH] = oH;
    }
  }
}

// ---------------------------------------------------------------------------
// f32 LIF chain (np-exact): v = fl(fl(AL*v)+fl(BL*cur)); s=(v-1>0); reset.
// spikes {0,1}; rates = count/500.   [proven R13]
// 64-thread blocks x 512: full CU coverage; unroll 20 for load batching.
// ---------------------------------------------------------------------------
__global__ __launch_bounds__(64) void lif32(
    const float* __restrict__ CUR, float* __restrict__ spikes,
    float* __restrict__ rates) {
  const int j = blockIdx.x * 64 + threadIdx.x;  // b*512 + n
  const float AL = (float)AL64, BL = (float)BL64;
  float v = 0.0f;
  int cnt = 0;
#pragma unroll 20
  for (int t = 0; t < TSTEPS; ++t) {
    float cur = CUR[(size_t)t * SNEUR + j];
    v = __fadd_rn(__fmul_rn(AL, v), __fmul_rn(BL, cur));
    int sp = __fadd_rn(v, -1.0f) > 0.0f;
    cnt += sp;
    spikes[(size_t)t * SNEUR + j] = sp ? 1.0f : 0.0f;
    v = sp ? 0.0f : v;
  }
  rates[j] = __fdiv_rn((float)cnt, 500.0f);
}

extern "C" void kernel_launch(void* const* d_in, const int* in_sizes, int n_in,
                              void* d_out, int out_size, void* d_ws, size_t ws_size,
                              hipStream_t stream) {
  float* out = (float*)d_out;  // f32: spikes [500*64*512] ++ rates [64*512]

  float flag = 0.0f;
  const float* X = nullptr;
  const float* W = nullptr;
  const float* AP = nullptr;
  if (n_in != 3) {
    flag = 11.0f;
  } else {
    for (int i = 0; i < 3; ++i) {
      if (in_sizes[i] == 16384000) X = (const float*)d_in[i];
      else if (in_sizes[i] == 262144) W = (const float*)d_in[i];
      else if (in_sizes[i] == 1) AP = (const float*)d_in[i];
    }
    if (!X || !W || !AP) flag = 13.0f;
    else if (out_size != (int)OUTN) flag = 17.0f;
    else if (ws_size < WS_NEED) flag = 23.0f;
  }
  if (flag != 0.0f) {
    fill_const_f32<<<dim3(2048), dim3(256), 0, stream>>>(out, OUTN, flag);
    return;
  }

  char* ws = (char*)d_ws;
  float* TR = (float*)(ws);                    // trace    [32000,512] f32
  float* PHx = (float*)(ws + BUF_BYTES);       // x-head -> CUR (in-place)
  float* PHt = (float*)(ws + 2 * BUF_BYTES);   // trace-head partial

  trace32<<<dim3(NCH / 64), dim3(64), 0, stream>>>(X, TR, AP);
  gemmDB<0><<<dim3(2000), dim3(256), 0, stream>>>(X, TR, W, PHx, PHt);
  gemmDB<1><<<dim3(2000), dim3(256), 0, stream>>>(X, TR, W, PHx, PHt);
  lif32<<<dim3(SNEUR / 64), dim3(64), 0, stream>>>(
      PHx, out, out + (size_t)TSTEPS * SNEUR);
}

// Round 22
// 664.311 us; speedup vs baseline: 1.0327x; 1.0327x over previous
//
#include <hip/hip_runtime.h>

typedef float f32x4 __attribute__((ext_vector_type(4)));

#define TSTEPS 500
#define BDIM 64
#define CIN 512
#define COUT 512
#define MTOT (TSTEPS * BDIM)   // 32000
#define NCH (BDIM * CIN)       // 32768
#define SNEUR (BDIM * COUT)    // 32768
#define OUTN ((size_t)TSTEPS * SNEUR + SNEUR)

#define AL64 0.95122942450071400909   // math.exp(-0.001/0.02), f64
#define BL64 (1.0 - AL64)

#define BUF_BYTES 65536000ull  // one [32000,512] f32 plane
#define WS_NEED (3ull * BUF_BYTES)

__global__ __launch_bounds__(256) void fill_const_f32(
    float* __restrict__ p, size_t n, float c) {
  size_t i = (size_t)blockIdx.x * 256 + threadIdx.x;
  const size_t stride = (size_t)gridDim.x * 256;
  for (; i < n; i += stride) p[i] = c;
}

// ---------------------------------------------------------------------------
// f32 trace scan (np-exact): tr = fl(fl(a*tr) + x)   [proven R13]
// 64-thread blocks x 512: covers all 256 CUs.
// ---------------------------------------------------------------------------
__global__ __launch_bounds__(64) void trace32(
    const float* __restrict__ X, float* __restrict__ TR,
    const float* __restrict__ alpha) {
  const int j = blockIdx.x * 64 + threadIdx.x;  // b*512 + ci
  const float a = fminf(fmaxf(alpha[0], 0.0f), 0.9999f);
  float tr = 0.0f;
#pragma unroll 20
  for (int t = 0; t < TSTEPS; ++t) {
    float x = X[(size_t)t * NCH + j];
    tr = __fadd_rn(__fmul_rn(a, tr), x);
    TR[(size_t)t * NCH + j] = tr;
  }
}

// ---------------------------------------------------------------------------
// Head/tail split GEMM, BK=32, single-buffered (R20 structure — best known,
// 499.7us total). ONLY change vs R20: __launch_bounds__(256, 4) — hint 4
// waves/EU (= 4 blocks/CU) to double resident waves for stall coverage.
// VGPR cap at this bound is 128; R20 measured 76, so no allocation change.
// Geometry: BM=64 x BN=128, 256 thr, 4x8/thread, 2 chain-sets (64 accs).
// Reduction order bit-identical to R13..R21: k = kt*32 + kg*4 + k2 strictly
// ascending per chain; split at k=384 (BLAS KC); combine
// fadd(fadd(xH,xT), fadd(tH,tT)). XCD-chunked swizzle (2000 = 8 x 250).
// PHASE 0: head (tiles 0..12) -> PHx/PHt partials.
// PHASE 1: tail (tiles 12..16), combine, CUR in-place over PHx.
// ---------------------------------------------------------------------------
template <int PHASE>
__global__ __launch_bounds__(256, 4) void gemmK32(
    const float* __restrict__ X, const float* __restrict__ TR,
    const float* __restrict__ W, float* __restrict__ PHx,
    float* __restrict__ PHt) {
  __shared__ __align__(16) float Asx[64][36];  // 64 rows x 32 k, padded
  __shared__ __align__(16) float Ast[64][36];
  __shared__ __align__(16) float Bs[32][132];  // 32 k x 128 n, padded
  const int tid = threadIdx.x;
  const int ty = tid >> 4, tx = tid & 15;

  const int fid = blockIdx.x;
  const int swz = (fid & 7) * 250 + (fid >> 3);
  const int bm = (swz >> 2) * 64;   // 500 row-panels
  const int bn = (swz & 3) * 128;   // 4 col-panels (fastest -> same XCD)

  const int ar = tid >> 2, akb = (tid & 3) * 8;  // A loader: 64 rows x 32 k
  const int bk = tid >> 3, bc4 = (tid & 7) * 4;  // B loader: 32 k x 128 n

  const int KT0 = PHASE ? 12 : 0;
  const int KT1 = PHASE ? 16 : 12;

  const float* gx = X + (size_t)(bm + ar) * CIN + KT0 * 32 + akb;
  const float* gt = TR + (size_t)(bm + ar) * CIN + KT0 * 32 + akb;
  const float* gw = W + (size_t)(KT0 * 32 + bk) * COUT + bn + bc4;

  float xA[4][8] = {{0.0f}}, tA[4][8] = {{0.0f}};

  for (int kt = KT0; kt < KT1; ++kt) {
    __syncthreads();  // previous compute done -> LDS reusable
    *(f32x4*)&Asx[ar][akb]     = *(const f32x4*)gx;
    *(f32x4*)&Asx[ar][akb + 4] = *(const f32x4*)(gx + 4);
    *(f32x4*)&Ast[ar][akb]     = *(const f32x4*)gt;
    *(f32x4*)&Ast[ar][akb + 4] = *(const f32x4*)(gt + 4);
#pragma unroll
    for (int q = 0; q < 4; ++q)
      *(f32x4*)&Bs[bk][bc4 + q * 32] = *(const f32x4*)(gw + q * 32);
    __syncthreads();  // tile ready
    gx += 32; gt += 32; gw += 32 * COUT;
#pragma unroll
    for (int kg = 0; kg < 8; ++kg) {
      f32x4 ax[4], at4[4];
#pragma unroll
      for (int i = 0; i < 4; ++i) {
        ax[i] = *(const f32x4*)&Asx[ty * 4 + i][kg * 4];
        at4[i] = *(const f32x4*)&Ast[ty * 4 + i][kg * 4];
      }
#pragma unroll
      for (int k2 = 0; k2 < 4; ++k2) {
        f32x4 bL = *(const f32x4*)&Bs[kg * 4 + k2][tx * 4];
        f32x4 bH = *(const f32x4*)&Bs[kg * 4 + k2][64 + tx * 4];
#pragma unroll
        for (int i = 0; i < 4; ++i)
#pragma unroll
          for (int j = 0; j < 4; ++j) {
            xA[i][j]     = fmaf(ax[i][k2], bL[j], xA[i][j]);
            xA[i][4 + j] = fmaf(ax[i][k2], bH[j], xA[i][4 + j]);
            tA[i][j]     = fmaf(at4[i][k2], bL[j], tA[i][j]);
            tA[i][4 + j] = fmaf(at4[i][k2], bH[j], tA[i][4 + j]);
          }
      }
    }
  }

#pragma unroll
  for (int i = 0; i < 4; ++i) {
    const size_t row = (size_t)(bm + ty * 4 + i);
    const size_t iL = row * COUT + bn + tx * 4;
    const size_t iH = row * COUT + bn + 64 + tx * 4;
    f32x4 xL, xH2, tL, tH2;
#pragma unroll
    for (int j = 0; j < 4; ++j) {
      xL[j] = xA[i][j];  xH2[j] = xA[i][4 + j];
      tL[j] = tA[i][j];  tH2[j] = tA[i][4 + j];
    }
    if (PHASE == 0) {
      *(f32x4*)&PHx[iL] = xL;   *(f32x4*)&PHx[iH] = xH2;
      *(f32x4*)&PHt[iL] = tL;   *(f32x4*)&PHt[iH] = tH2;
    } else {
      f32x4 hxL = *(const f32x4*)&PHx[iL];
      f32x4 hxH = *(const f32x4*)&PHx[iH];
      f32x4 htL = *(const f32x4*)&PHt[iL];
      f32x4 htH = *(const f32x4*)&PHt[iH];
      f32x4 oL, oH;
#pragma unroll
      for (int j = 0; j < 4; ++j) {
        // cur = fadd(fadd(xH,xT), fadd(tH,tT))  — proven combine order
        oL[j] = __fadd_rn(__fadd_rn(hxL[j], xL[j]), __fadd_rn(htL[j], tL[j]));
        oH[j] = __fadd_rn(__fadd_rn(hxH[j], xH2[j]), __fadd_rn(htH[j], tH2[j]));
      }
      *(f32x4*)&PHx[iL] = oL;  // in-place: PHx becomes CUR
      *(f32x4*)&PHx[iH] = oH;
    }
  }
}

// ---------------------------------------------------------------------------
// f32 LIF chain (np-exact): v = fl(fl(AL*v)+fl(BL*cur)); s=(v-1>0); reset.
// spikes {0,1}; rates = count/500.   [proven R13]
// ---------------------------------------------------------------------------
__global__ __launch_bounds__(64) void lif32(
    const float* __restrict__ CUR, float* __restrict__ spikes,
    float* __restrict__ rates) {
  const int j = blockIdx.x * 64 + threadIdx.x;  // b*512 + n
  const float AL = (float)AL64, BL = (float)BL64;
  float v = 0.0f;
  int cnt = 0;
#pragma unroll 20
  for (int t = 0; t < TSTEPS; ++t) {
    float cur = CUR[(size_t)t * SNEUR + j];
    v = __fadd_rn(__fmul_rn(AL, v), __fmul_rn(BL, cur));
    int sp = __fadd_rn(v, -1.0f) > 0.0f;
    cnt += sp;
    spikes[(size_t)t * SNEUR + j] = sp ? 1.0f : 0.0f;
    v = sp ? 0.0f : v;
  }
  rates[j] = __fdiv_rn((float)cnt, 500.0f);
}

extern "C" void kernel_launch(void* const* d_in, const int* in_sizes, int n_in,
                              void* d_out, int out_size, void* d_ws, size_t ws_size,
                              hipStream_t stream) {
  float* out = (float*)d_out;  // f32: spikes [500*64*512] ++ rates [64*512]

  float flag = 0.0f;
  const float* X = nullptr;
  const float* W = nullptr;
  const float* AP = nullptr;
  if (n_in != 3) {
    flag = 11.0f;
  } else {
    for (int i = 0; i < 3; ++i) {
      if (in_sizes[i] == 16384000) X = (const float*)d_in[i];
      else if (in_sizes[i] == 262144) W = (const float*)d_in[i];
      else if (in_sizes[i] == 1) AP = (const float*)d_in[i];
    }
    if (!X || !W || !AP) flag = 13.0f;
    else if (out_size != (int)OUTN) flag = 17.0f;
    else if (ws_size < WS_NEED) flag = 23.0f;
  }
  if (flag != 0.0f) {
    fill_const_f32<<<dim3(2048), dim3(256), 0, stream>>>(out, OUTN, flag);
    return;
  }

  char* ws = (char*)d_ws;
  float* TR = (float*)(ws);                    // trace    [32000,512] f32
  float* PHx = (float*)(ws + BUF_BYTES);       // x-head -> CUR (in-place)
  float* PHt = (float*)(ws + 2 * BUF_BYTES);   // trace-head partial

  trace32<<<dim3(NCH / 64), dim3(64), 0, stream>>>(X, TR, AP);
  gemmK32<0><<<dim3(2000), dim3(256), 0, stream>>>(X, TR, W, PHx, PHt);
  gemmK32<1><<<dim3(2000), dim3(256), 0, stream>>>(X, TR, W, PHx, PHt);
  lif32<<<dim3(SNEUR / 64), dim3(64), 0, stream>>>(
      PHx, out, out + (size_t)TSTEPS * SNEUR);
}